// Round 20
// baseline (624.279 us; speedup 1.0000x reference)
//
#include <hip/hip_runtime.h>
#include <hip/hip_bf16.h>
#include <math.h>

#define H_ 16
#define HIDDEN_ 1024
#define BATCH_ 4
#define T_ 2048
#define M_ (BATCH_ * T_)   // 8192
#define QS_ 3328           // fused projection row stride: q|k|v|f1|g1|b|pad

typedef __attribute__((ext_vector_type(8))) __bf16 bf16x8;
typedef __attribute__((ext_vector_type(4))) float f32x4;

__device__ __forceinline__ float fexp_(float x) { return __expf(x); }
__device__ __forceinline__ float frcp_(float x) { return __builtin_amdgcn_rcpf(x); }
__device__ __forceinline__ float wave_sum64(float v) {
  #pragma unroll
  for (int m = 32; m >= 1; m >>= 1) v += __shfl_xor(v, m, 64);
  return v;
}
__device__ __forceinline__ float sigmoidf_(float x) { return frcp_(1.f + fexp_(-x)); }
__device__ __forceinline__ float siluf_(float x) { return x * frcp_(1.f + fexp_(-x)); }
__device__ __forceinline__ float bf2f(ushort u) {
  unsigned int x = ((unsigned int)u) << 16;
  return __builtin_bit_cast(float, x);
}
__device__ __forceinline__ ushort f2bf(float f) {   // RNE
  unsigned int x = __builtin_bit_cast(unsigned int, f);
  unsigned int r = (x + 0x7fffu + ((x >> 16) & 1u)) >> 16;
  return (ushort)r;
}
__device__ __forceinline__ void ub2_(uint u, float f[2]) {
  f[0] = bf2f((ushort)u); f[1] = bf2f((ushort)(u >> 16));
}
__device__ __forceinline__ void ub4_(uint2 u, float f[4]) {
  f[0] = bf2f((ushort)u.x); f[1] = bf2f((ushort)(u.x >> 16));
  f[2] = bf2f((ushort)u.y); f[3] = bf2f((ushort)(u.y >> 16));
}
__device__ __forceinline__ void ub8_(uint4 u, float* f) {
  f[0] = bf2f((ushort)u.x); f[1] = bf2f((ushort)(u.x >> 16));
  f[2] = bf2f((ushort)u.y); f[3] = bf2f((ushort)(u.y >> 16));
  f[4] = bf2f((ushort)u.z); f[5] = bf2f((ushort)(u.z >> 16));
  f[6] = bf2f((ushort)u.w); f[7] = bf2f((ushort)(u.w >> 16));
}
__device__ __forceinline__ uint pk2_(float a, float b) {
  return (uint)f2bf(a) | ((uint)f2bf(b) << 16);
}
__device__ __forceinline__ uint2 pk4_(float a, float b, float c, float d) {
  return make_uint2((uint)f2bf(a) | ((uint)f2bf(b) << 16),
                    (uint)f2bf(c) | ((uint)f2bf(d) << 16));
}
__device__ __forceinline__ uint4 pk8_(const float* t) {
  uint4 r;
  r.x = (uint)f2bf(t[0]) | ((uint)f2bf(t[1]) << 16);
  r.y = (uint)f2bf(t[2]) | ((uint)f2bf(t[3]) << 16);
  r.z = (uint)f2bf(t[4]) | ((uint)f2bf(t[5]) << 16);
  r.w = (uint)f2bf(t[6]) | ((uint)f2bf(t[7]) << 16);
  return r;
}
// async global -> LDS, 16B per lane
__device__ __forceinline__ void gl16(const ushort* g, ushort* l) {
  __builtin_amdgcn_global_load_lds(
      (const __attribute__((address_space(1))) unsigned int*)g,
      (__attribute__((address_space(3))) unsigned int*)l, 16, 0, 0);
}

// ---------------------------------------------------------------------------
// pack_all: ONE launch for all input-side packing incl. Wo (was 2 launches).
// Region decode by blockIdx; disjoint outputs; pad rows zeroed here.
// ---------------------------------------------------------------------------
__global__ __launch_bounds__(256) void pack_all(
    const float* __restrict__ hs,
    const float* __restrict__ Wq, const float* __restrict__ Wk,
    const float* __restrict__ Wv, const float* __restrict__ Wf1,
    const float* __restrict__ Wg1, const float* __restrict__ Wb,
    const float* __restrict__ Wf2, const float* __restrict__ Wg2,
    const float* __restrict__ Wo,
    ushort* __restrict__ hs1, ushort* __restrict__ Wqkvfgb,
    ushort* __restrict__ Wf2_1, ushort* __restrict__ Wg2_1,
    ushort* __restrict__ Wo1) {
  int blk = blockIdx.x;
  // R0: hs [8192,1024] contiguous copy-cast — 32768 blocks
  if (blk < 32768) {
    size_t tid = (size_t)blk * 256 + threadIdx.x;
    hs1[tid] = f2bf(hs[tid]);
    return;
  }
  blk -= 32768;
  // R1: Wq/Wk/Wv transpose [1024,1024] -> rows [w*1024..) — 3 x 4096 blocks
  if (blk < 12288) {
    int w = blk >> 12;
    size_t tid = (size_t)(blk & 4095) * 256 + threadIdx.x;
    int k = (int)(tid & 1023), n = (int)(tid >> 10);
    const float* W = (w == 0) ? Wq : (w == 1) ? Wk : Wv;
    Wqkvfgb[((size_t)w * 1024 + n) * 1024 + k] = f2bf(W[(size_t)k * 1024 + n]);
    return;
  }
  blk -= 12288;
  // R2: Wf1 [1024,64] -> rows 3072.. — 256 blocks
  if (blk < 256) {
    size_t tid = (size_t)blk * 256 + threadIdx.x;
    int k = (int)(tid & 1023), n = (int)(tid >> 10);
    Wqkvfgb[(size_t)(3072 + n) * 1024 + k] = f2bf(Wf1[(size_t)k * 64 + n]);
    return;
  }
  blk -= 256;
  // R3: Wg1 -> rows 3136.. — 256 blocks
  if (blk < 256) {
    size_t tid = (size_t)blk * 256 + threadIdx.x;
    int k = (int)(tid & 1023), n = (int)(tid >> 10);
    Wqkvfgb[(size_t)(3136 + n) * 1024 + k] = f2bf(Wg1[(size_t)k * 64 + n]);
    return;
  }
  blk -= 256;
  // R4: Wb [1024,16] -> rows 3200.. — 64 blocks
  if (blk < 64) {
    size_t tid = (size_t)blk * 256 + threadIdx.x;
    int k = (int)(tid & 1023), n = (int)(tid >> 10);
    Wqkvfgb[(size_t)(3200 + n) * 1024 + k] = f2bf(Wb[(size_t)k * 16 + n]);
    return;
  }
  blk -= 64;
  // R5: zero pad rows 3216..3327 — 448 blocks
  if (blk < 448) {
    size_t tid = (size_t)blk * 256 + threadIdx.x;
    Wqkvfgb[(size_t)3216 * 1024 + tid] = 0;
    return;
  }
  blk -= 448;
  // R6: Wf2 [64,1024] -> Wf2_1[n][k], rowStride 64 — 256 blocks
  if (blk < 256) {
    size_t tid = (size_t)blk * 256 + threadIdx.x;
    int k = (int)(tid & 63), n = (int)(tid >> 6);
    Wf2_1[(size_t)n * 64 + k] = f2bf(Wf2[(size_t)k * 1024 + n]);
    return;
  }
  blk -= 256;
  // R7: Wg2 -> Wg2_1 — 256 blocks
  if (blk < 256) {
    size_t tid = (size_t)blk * 256 + threadIdx.x;
    int k = (int)(tid & 63), n = (int)(tid >> 6);
    Wg2_1[(size_t)n * 64 + k] = f2bf(Wg2[(size_t)k * 1024 + n]);
    return;
  }
  blk -= 256;
  // R8: Wo transpose [1024,1024] -> Wo1[n][k] — 4096 blocks
  {
    size_t tid = (size_t)blk * 256 + threadIdx.x;
    int k = (int)(tid & 1023), n = (int)(tid >> 10);
    Wo1[(size_t)n * 1024 + k] = f2bf(Wo[(size_t)k * 1024 + n]);
  }
}
#define PACK_ALL_BLOCKS (32768 + 12288 + 256 + 256 + 64 + 448 + 256 + 256 + 4096)

// ---------------------------------------------------------------------------
// bf16 MFMA GEMM, m97 structure + lda + bijective XCD swizzle (nwg%8==0).
// ---------------------------------------------------------------------------
template <typename OutT>
__global__ __launch_bounds__(256) void gemm_glds(
    const ushort* __restrict__ A, int lda, const ushort* __restrict__ Bt,
    const float* __restrict__ bias, OutT* __restrict__ C,
    int M, int N, int K) {
  __shared__ ushort As[128 * 32];
  __shared__ ushort Bs[128 * 32];
  const int tid = threadIdx.x;
  const int gx = gridDim.x;
  const int nwg = gx * gridDim.y;
  const int flat = blockIdx.y * gx + blockIdx.x;
  const int swz = (flat & 7) * (nwg >> 3) + (flat >> 3);
  const int bm = (swz % gx) * 128, bn = (swz / gx) * 128;
  const int wid = tid >> 6, lane = tid & 63;
  const int wm = (wid >> 1) * 64, wn = (wid & 1) * 64;
  const int fr = lane & 15, fq = lane >> 4;
  const int srow = wid * 32 + (lane >> 2);
  const int scol = (lane & 3) * 8;

  f32x4 acc[4][4] = {};

  for (int k0 = 0; k0 < K; k0 += 32) {
    const ushort* gA = A + (size_t)(bm + srow) * lda + k0 + scol;
    const ushort* gB = Bt + (size_t)(bn + srow) * K + k0 + scol;
    gl16(gA, &As[(wid * 32) * 32]);
    gl16(gA + (size_t)16 * lda, &As[(wid * 32 + 16) * 32]);
    gl16(gB, &Bs[(wid * 32) * 32]);
    gl16(gB + (size_t)16 * K, &Bs[(wid * 32 + 16) * 32]);
    __syncthreads();

    bf16x8 af[4], bfr[4];
    #pragma unroll
    for (int i = 0; i < 4; i++) af[i] = *(const bf16x8*)&As[(wm + i * 16 + fr) * 32 + fq * 8];
    #pragma unroll
    for (int j = 0; j < 4; j++) bfr[j] = *(const bf16x8*)&Bs[(wn + j * 16 + fr) * 32 + fq * 8];
    #pragma unroll
    for (int i = 0; i < 4; i++)
      #pragma unroll
      for (int j = 0; j < 4; j++)
        acc[i][j] = __builtin_amdgcn_mfma_f32_16x16x32_bf16(af[i], bfr[j], acc[i][j], 0, 0, 0);
    __syncthreads();
  }

  #pragma unroll
  for (int i = 0; i < 4; i++) {
    #pragma unroll
    for (int j = 0; j < 4; j++) {
      int col = bn + wn + j * 16 + fr;
      float bv = bias ? bias[col] : 0.f;
      #pragma unroll
      for (int r = 0; r < 4; r++) {
        int row = bm + wm + i * 16 + fq * 4 + r;
        float v = acc[i][j][r] + bv;
        if constexpr (sizeof(OutT) == 2) {
          ((ushort*)C)[(size_t)row * N + col] = f2bf(v);
        } else {
          ((float*)C)[(size_t)row * N + col] = v;
        }
      }
    }
  }
}

// unpack element u (0..15) from a 4-row packed conv window x[8] (2 uint4/row)
#define XROW(x, tap, u) \
  bf2f((ushort)(((u) & 1) ? (((const uint*)&(x)[(tap) * 2 + ((u) >> 3)])[((u) >> 1) & 3] >> 16) \
                          : ((const uint*)&(x)[(tap) * 2 + ((u) >> 3)])[((u) >> 1) & 3]))
#define TAPW(w, tap) ((tap) == 0 ? (w).x : (tap) == 1 ? (w).y : (tap) == 2 ? (w).z : (w).w)

// ---------------------------------------------------------------------------
// prep: R18/R19 version (proven 190us / normal traffic). DO NOT touch.
// ---------------------------------------------------------------------------
__global__ __launch_bounds__(256, 3) void prep(
    const ushort* __restrict__ qkv, const ushort* __restrict__ grawB,
    const float* __restrict__ qcw, const float* __restrict__ qcb,
    const float* __restrict__ kcw, const float* __restrict__ kcb,
    const float* __restrict__ vcw, const float* __restrict__ vcb,
    const float* __restrict__ A_log, const float* __restrict__ dtb,
    ushort* __restrict__ mMGSG, ushort* __restrict__ mWkB,
    ushort* __restrict__ mWqBv, float* __restrict__ geG) {
  const int bh = blockIdx.x, ch = blockIdx.y;
  const int b = bh >> 4, h = bh & 15;
  const int i = bh * 32 + ch;
  const int t0 = ch * 64;
  const int tid = threadIdx.x;
  const int wA = tid >> 6, tA = tid & 63;
  const int tTh = tid >> 2, c4 = tid & 3, kb = c4 * 16;
  const int c0 = h * 64 + kb;

  __shared__ __align__(16) ushort KtU[64][72];
  __shared__ __align__(16) ushort KhU[64][72];
  __shared__ __align__(16) ushort QtU[64][72];
  __shared__ __align__(16) float cM[64][72];
  __shared__ __align__(16) float dlog[17][68];
  __shared__ float betaL[64];
  ushort* cMu = (ushort*)&cM[0][0];
  ushort (*MqkRM)[72] = (ushort(*)[72])cMu;
  ushort (*MkkT)[72] = (ushort(*)[72])(cMu + 64 * 72);
  ushort (*Gt)[72] = KtU;
  ushort (*KhET)[72] = QtU;

  // ---- PH0: conv+SiLU+norm for q,k ----
  {
    const uint4 z4 = make_uint4(0, 0, 0, 0);
    {
      uint4 x[8];
      #pragma unroll
      for (int tap = 0; tap < 4; tap++) {
        int tr = t0 + tTh - 3 + tap;
        if (tr >= 0) {
          const uint4* p = (const uint4*)(qkv + (size_t)(b * T_ + tr) * QS_ + c0);
          x[tap * 2] = p[0]; x[tap * 2 + 1] = p[1];
        } else { x[tap * 2] = z4; x[tap * 2 + 1] = z4; }
      }
      float qa[16], s = 0.f;
      #pragma unroll
      for (int u = 0; u < 16; u++) {
        float4 w = ((const float4*)qcw)[c0 + u];
        float a = qcb[c0 + u];
        #pragma unroll
        for (int tap = 0; tap < 4; tap++) a += XROW(x, tap, u) * TAPW(w, tap);
        a = siluf_(a);
        qa[u] = a; s += a * a;
      }
      s += __shfl_xor(s, 1, 64); s += __shfl_xor(s, 2, 64);
      float qs = 0.125f / (sqrtf(s) + 1e-6f);
      #pragma unroll
      for (int u = 0; u < 16; u++) qa[u] *= qs;
      *(uint4*)&QtU[tTh][kb] = pk8_(&qa[0]);
      *(uint4*)&QtU[tTh][kb + 8] = pk8_(&qa[8]);
    }
    {
      uint4 x[8];
      #pragma unroll
      for (int tap = 0; tap < 4; tap++) {
        int tr = t0 + tTh - 3 + tap;
        if (tr >= 0) {
          const uint4* p = (const uint4*)(qkv + (size_t)(b * T_ + tr) * QS_ + 1024 + c0);
          x[tap * 2] = p[0]; x[tap * 2 + 1] = p[1];
        } else { x[tap * 2] = z4; x[tap * 2 + 1] = z4; }
      }
      float ka[16], s = 0.f;
      #pragma unroll
      for (int u = 0; u < 16; u++) {
        float4 w = ((const float4*)kcw)[c0 + u];
        float a = kcb[c0 + u];
        #pragma unroll
        for (int tap = 0; tap < 4; tap++) a += XROW(x, tap, u) * TAPW(w, tap);
        a = siluf_(a);
        ka[u] = a; s += a * a;
      }
      s += __shfl_xor(s, 1, 64); s += __shfl_xor(s, 2, 64);
      float ks = frcp_(sqrtf(s) + 1e-6f);
      #pragma unroll
      for (int u = 0; u < 16; u++) ka[u] *= ks;
      *(uint4*)&KtU[tTh][kb] = pk8_(&ka[0]);
      *(uint4*)&KtU[tTh][kb + 8] = pk8_(&ka[8]);
    }
    {
      float Aexp = fexp_(A_log[h]);
      const ushort* gr = grawB + (size_t)(b * T_ + t0 + tTh) * 1024 + c0;
      uint4 ga = *(const uint4*)gr;
      uint4 gb = *(const uint4*)(gr + 8);
      float xv[16];
      ub8_(ga, &xv[0]); ub8_(gb, &xv[8]);
      #pragma unroll
      for (int u = 0; u < 16; u++) {
        float x = xv[u] + dtb[c0 + u];
        float sp = (x > 20.f) ? x : __logf(1.f + fexp_(x));
        cM[tTh][kb + u] = -Aexp * sp;
      }
      if (tid < 64)
        betaL[tid] = sigmoidf_(bf2f(qkv[(size_t)(b * T_ + t0 + tid) * QS_ + 3200 + h]));
    }
  }
  __syncthreads();
  // ---- PH2: cumsum within quarters ----
  {
    const int q = wA, k = tA;
    float run = 0.f;
    #pragma unroll
    for (int u = 0; u < 16; u++) { run += cM[q * 16 + u][k]; cM[q * 16 + u][k] = run; }
    dlog[q][k] = run;
  }
  __syncthreads();
  // ---- PH3: segment offsets ----
  {
    const int q = wA, k = tA;
    if (q > 0) {
      float off = dlog[0][k];
      if (q > 1) off += dlog[1][k];
      if (q > 2) off += dlog[2][k];
      #pragma unroll
      for (int u = 0; u < 16; u++) cM[q * 16 + u][k] += off;
    }
  }
  __syncthreads();
  // ---- PH4: block-base log decays ----
  for (int idx = tid; idx < 17 * 64; idx += 256) {
    int P = idx >> 6, k = idx & 63;
    dlog[P][k] = (P == 0) ? 0.f : cM[4 * P - 1][k];
  }
  __syncthreads();
  // ---- PH5: K~/K^/Q~ ----
  {
    const int P5 = tTh >> 2;
    float knv[16], qnv[16];
    ub8_(*(const uint4*)&KtU[tTh][kb], &knv[0]);
    ub8_(*(const uint4*)&KtU[tTh][kb + 8], &knv[8]);
    ub8_(*(const uint4*)&QtU[tTh][kb], &qnv[0]);
    ub8_(*(const uint4*)&QtU[tTh][kb + 8], &qnv[8]);
    float ktv[16], khv[16], qtv[16];
    #pragma unroll
    for (int u = 0; u < 16; u++) {
      int k = kb + u;
      float c = cM[tTh][k], d = dlog[P5][k];
      float e1 = fexp_(c - d);
      float e2 = fexp_(d - c);
      ktv[u] = knv[u] * e1;
      khv[u] = knv[u] * e2;
      qtv[u] = qnv[u] * e1;
    }
    *(uint4*)&KtU[tTh][kb] = pk8_(&ktv[0]);
    *(uint4*)&KtU[tTh][kb + 8] = pk8_(&ktv[8]);
    *(uint4*)&KhU[tTh][kb] = pk8_(&khv[0]);
    *(uint4*)&KhU[tTh][kb + 8] = pk8_(&khv[8]);
    *(uint4*)&QtU[tTh][kb] = pk8_(&qtv[0]);
    *(uint4*)&QtU[tTh][kb + 8] = pk8_(&qtv[8]);
  }
  __syncthreads();
  // ---- PH6: Wq/WkB/bv/ge outputs + Mqk-upper zeroing + M-build ----
  {
    const int P = tTh >> 2;
    float bt = betaL[tTh];
    float qtv[16], ktv[16];
    ub8_(*(const uint4*)&QtU[tTh][kb], &qtv[0]);
    ub8_(*(const uint4*)&QtU[tTh][kb + 8], &qtv[8]);
    ub8_(*(const uint4*)&KtU[tTh][kb], &ktv[0]);
    ub8_(*(const uint4*)&KtU[tTh][kb + 8], &ktv[8]);
    float tq[16], tk[16];
    #pragma unroll
    for (int u = 0; u < 16; u++) {
      int k = kb + u;
      float e = fexp_(dlog[P][k]);
      tq[u] = qtv[u] * e;
      tk[u] = bt * ktv[u] * e;
    }
    ushort* pq = mWqBv + (size_t)i * 8192 + tTh * 64 + kb;
    ushort* pk = mWkB + (size_t)i * 4096 + tTh * 64 + kb;
    *(uint4*)&pq[0] = pk8_(&tq[0]);
    *(uint4*)&pq[8] = pk8_(&tq[8]);
    *(uint4*)&pk[0] = pk8_(&tk[0]);
    *(uint4*)&pk[8] = pk8_(&tk[8]);

    {
      const uint4 z4 = make_uint4(0, 0, 0, 0);
      uint4 x[8];
      #pragma unroll
      for (int tap = 0; tap < 4; tap++) {
        int tr = t0 + tTh - 3 + tap;
        if (tr >= 0) {
          const uint4* p = (const uint4*)(qkv + (size_t)(b * T_ + tr) * QS_ + 2048 + c0);
          x[tap * 2] = p[0]; x[tap * 2 + 1] = p[1];
        } else { x[tap * 2] = z4; x[tap * 2 + 1] = z4; }
      }
      float av[16];
      #pragma unroll
      for (int u = 0; u < 16; u++) {
        float4 w = ((const float4*)vcw)[c0 + u];
        float a = vcb[c0 + u];
        #pragma unroll
        for (int tap = 0; tap < 4; tap++) a += XROW(x, tap, u) * TAPW(w, tap);
        av[u] = bt * siluf_(a);
      }
      ushort* pb = mWqBv + (size_t)i * 8192 + 4096 + tTh * 64 + kb;
      *(uint4*)&pb[0] = pk8_(&av[0]);
      *(uint4*)&pb[8] = pk8_(&av[8]);
    }

    if (tid < 64) geG[(size_t)i * 64 + tid] = fexp_(dlog[16][tid]);

    for (int idx = tid; idx < 64 * 72; idx += 256) {
      int t = idx / 72, s = idx - t * 72;
      if (s >= 64 || (s >> 2) > (t >> 2)) MqkRM[t][s] = 0;
    }

    // M-build: 272 4x4 tiles, R = e^{dP-dJ} <= 1 on the fly
    for (int tile = tid; tile < 272; tile += 256) {
      int mq = (tile >= 136) ? 1 : 0;
      int f = tile - mq * 136;
      int rem = f, P2 = 0;
      while (rem >= P2 + 1) { rem -= P2 + 1; ++P2; }
      int J = rem;
      const ushort (*Xr)[72] = mq ? QtU : KtU;
      float acc[4][4] = {};
      for (int kc = 0; kc < 16; kc++) {
        float av0[4], av1[4], av2[4], av3[4];
        ub4_(*(const uint2*)&Xr[4 * P2 + 0][kc * 4], av0);
        ub4_(*(const uint2*)&Xr[4 * P2 + 1][kc * 4], av1);
        ub4_(*(const uint2*)&Xr[4 * P2 + 2][kc * 4], av2);
        ub4_(*(const uint2*)&Xr[4 * P2 + 3][kc * 4], av3);
        float4 dp = *(const float4*)&dlog[P2][kc * 4];
        float4 dj = *(const float4*)&dlog[J][kc * 4];
        float rv[4] = {fexp_(dp.x - dj.x), fexp_(dp.y - dj.y),
                       fexp_(dp.z - dj.z), fexp_(dp.w - dj.w)};
        #pragma unroll
        for (int c = 0; c < 4; c++) {
          float kv[4];
          ub4_(*(const uint2*)&KhU[4 * J + c][kc * 4], kv);
          float bx = kv[0] * rv[0], by = kv[1] * rv[1], bz = kv[2] * rv[2], bw = kv[3] * rv[3];
          acc[0][c] += av0[0] * bx + av0[1] * by + av0[2] * bz + av0[3] * bw;
          acc[1][c] += av1[0] * bx + av1[1] * by + av1[2] * bz + av1[3] * bw;
          acc[2][c] += av2[0] * bx + av2[1] * by + av2[2] * bz + av2[3] * bw;
          acc[3][c] += av3[0] * bx + av3[1] * by + av3[2] * bz + av3[3] * bw;
        }
      }
      if (mq && P2 == J) {
        #pragma unroll
        for (int c = 0; c < 4; c++)
          #pragma unroll
          for (int r = 0; r < 4; r++)
            if (c > r) acc[r][c] = 0.f;
      }
      if (mq) {
        #pragma unroll
        for (int r = 0; r < 4; r++)
          *(uint2*)&MqkRM[4 * P2 + r][4 * J] =
              pk4_(acc[r][0], acc[r][1], acc[r][2], acc[r][3]);
      } else {
        #pragma unroll
        for (int c = 0; c < 4; c++) {
          uint2 w;
          w.x = (uint)f2bf(acc[0][c]) | ((uint)f2bf(acc[1][c]) << 16);
          w.y = (uint)f2bf(acc[2][c]) | ((uint)f2bf(acc[3][c]) << 16);
          *(uint2*)&MkkT[4 * J + c][4 * P2] = w;
        }
      }
    }
  }
  __syncthreads();
  // ---- PH7: KhET (transposed) into QtU + G-solve writing Gt (transposed) ----
  for (int idx = tid; idx < 4096; idx += 256) {
    int k = idx >> 6, s = idx & 63;
    KhET[k][s] = f2bf(bf2f(KhU[s][k]) * fexp_(dlog[16][k] - dlog[s >> 2][k]));
  }
  {
    const int j = tTh, q = c4;
    float acc[16], gsv[16];
    #pragma unroll
    for (int u = 0; u < 16; u++) { acc[u] = 0.f; gsv[u] = 0.f; }
    for (int s = 0; s < 64; s++) {
      int q0 = s >> 4;
      float g = 0.f;
      if (q == q0) {
        g = ((s == j) ? 1.f : 0.f) - betaL[s] * acc[s & 15];
        gsv[s & 15] = g;
      }
      g = __shfl(g, 4 * (j & 15) + q0, 64);
      #pragma unroll
      for (int u = 0; u < 4; u++) {
        uint2 m2 = *(const uint2*)&MkkT[s][q * 16 + u * 4];
        acc[u * 4 + 0] += bf2f((ushort)m2.x) * g;
        acc[u * 4 + 1] += bf2f((ushort)(m2.x >> 16)) * g;
        acc[u * 4 + 2] += bf2f((ushort)m2.y) * g;
        acc[u * 4 + 3] += bf2f((ushort)(m2.y >> 16)) * g;
      }
    }
    *(uint4*)&Gt[j][q * 16] = pk8_(&gsv[0]);
    *(uint4*)&Gt[j][q * 16 + 8] = pk8_(&gsv[8]);
  }
  __syncthreads();
  // ---- PH8 (MFMA): MG = tril(Mqk)@G, SG = KhET@G ----
  {
    const int wid = tid >> 6, lane = tid & 63;
    const int fr = lane & 15, fq = lane >> 4;
    const int wrow = wid * 16;
    bf16x8 aM[2], aS[2];
    #pragma unroll
    for (int kt = 0; kt < 2; kt++) {
      aM[kt] = *(const bf16x8*)&MqkRM[wrow + fr][kt * 32 + fq * 8];
      aS[kt] = *(const bf16x8*)&KhET[wrow + fr][kt * 32 + fq * 8];
    }
    #pragma unroll
    for (int jt = 0; jt < 4; jt++) {
      bf16x8 bG[2];
      #pragma unroll
      for (int kt = 0; kt < 2; kt++)
        bG[kt] = *(const bf16x8*)&Gt[jt * 16 + fr][kt * 32 + fq * 8];
      f32x4 accM = {}, accS = {};
      #pragma unroll
      for (int kt = 0; kt < 2; kt++) {
        accM = __builtin_amdgcn_mfma_f32_16x16x32_bf16(aM[kt], bG[kt], accM, 0, 0, 0);
        accS = __builtin_amdgcn_mfma_f32_16x16x32_bf16(aS[kt], bG[kt], accS, 0, 0, 0);
      }
      #pragma unroll
      for (int r = 0; r < 4; r++) {
        int row = wrow + fq * 4 + r, col = jt * 16 + fr;
        mMGSG[(size_t)i * 8192 + row * 64 + col] = f2bf(accM[r]);
        mMGSG[(size_t)i * 8192 + 4096 + row * 64 + col] = f2bf(accS[r]);
      }
    }
  }
}

// ---------------------------------------------------------------------------
// scan: 512 threads, 2 v-cols/thread. Grid (64 bh, 4 vq).
// ---------------------------------------------------------------------------
__global__ __launch_bounds__(512) void scan(
    const ushort* __restrict__ mMGSG, const ushort* __restrict__ mWkB,
    const ushort* __restrict__ mWqBv, const float* __restrict__ geG,
    ushort* __restrict__ oG) {
  const int bh = blockIdx.x, vq = blockIdx.y;
  const int tid = threadIdx.x;
  const int tTh = tid >> 3, c8 = tid & 7, lvi = c8 * 2;
  const int r0 = tid >> 3, cc = (tid & 7) * 8;

  __shared__ ushort MGs[64][72], SGs[64][72], WkBs[64][72], Wqs[64][72];
  __shared__ __align__(16) float Sl[64][20], rl[64][20];
  __shared__ float geL[64];

  Sl[tTh][lvi] = 0.f; Sl[tTh][lvi + 1] = 0.f;

  const size_t i0 = (size_t)bh * 32;
  {
    uint4 a0 = *(const uint4*)&mMGSG[i0 * 8192 + tid * 8];
    uint4 b0 = *(const uint4*)&mMGSG[i0 * 8192 + 4096 + tid * 8];
    uint4 c0 = *(const uint4*)&mWkB[i0 * 4096 + (tid & 511) * 8];
    uint4 d0 = *(const uint4*)&mWqBv[i0 * 8192 + tid * 8];
    *(uint4*)&MGs[r0][cc] = a0;
    *(uint4*)&SGs[r0][cc] = b0;
    *(uint4*)&WkBs[r0][cc] = c0;
    *(uint4*)&Wqs[r0][cc] = d0;
    if (tid < 64) geL[tid] = geG[i0 * 64 + tid];
  }
  uint bvCur = *(const uint*)&mWqBv[i0 * 8192 + 4096 + tTh * 64 + vq * 16 + lvi];
  __syncthreads();

  for (int ch = 0; ch < 32; ch++) {
    const size_t i = i0 + ch;
    uint4 p0, p1, p2, p3;
    uint pbv;
    float pge = 0.f;
    if (ch < 31) {
      const size_t i2 = i + 1;
      p0 = *(const uint4*)&mMGSG[i2 * 8192 + tid * 8];
      p1 = *(const uint4*)&mMGSG[i2 * 8192 + 4096 + tid * 8];
      p2 = *(const uint4*)&mWkB[i2 * 4096 + tid * 8];
      p3 = *(const uint4*)&mWqBv[i2 * 8192 + tid * 8];
      pbv = *(const uint*)&mWqBv[i2 * 8192 + 4096 + tTh * 64 + vq * 16 + lvi];
      if (tid < 64) pge = geG[i2 * 64 + tid];
    }
    float rv0, rv1;
    {
      float b2[2]; ub2_(bvCur, b2); rv0 = b2[0]; rv1 = b2[1];
    }
    #pragma unroll
    for (int kc = 0; kc < 16; kc++) {
      float w4[4];
      ub4_(*(const uint2*)&WkBs[tTh][kc * 4], w4);
      #pragma unroll
      for (int jj = 0; jj < 4; jj++) {
        float2 s2 = *(const float2*)&Sl[kc * 4 + jj][lvi];
        rv0 -= w4[jj] * s2.x; rv1 -= w4[jj] * s2.y;
      }
    }
    rl[tTh][lvi] = rv0; rl[tTh][lvi + 1] = rv1;
    __syncthreads();
    {
      float ov0 = 0.f, ov1 = 0.f;
      #pragma unroll
      for (int sc = 0; sc < 16; sc++) {
        float m4[4];
        ub4_(*(const uint2*)&MGs[tTh][sc * 4], m4);
        #pragma unroll
        for (int jj = 0; jj < 4; jj++) {
          float2 r2 = *(const float2*)&rl[sc * 4 + jj][lvi];
          ov0 += m4[jj] * r2.x; ov1 += m4[jj] * r2.y;
        }
      }
      #pragma unroll
      for (int kc = 0; kc < 16; kc++) {
        float q4[4];
        ub4_(*(const uint2*)&Wqs[tTh][kc * 4], q4);
        #pragma unroll
        for (int jj = 0; jj < 4; jj++) {
          float2 s2 = *(const float2*)&Sl[kc * 4 + jj][lvi];
          ov0 += q4[jj] * s2.x; ov1 += q4[jj] * s2.y;
        }
      }
      *(uint*)&oG[i * 4096 + tTh * 64 + vq * 16 + lvi] = pk2_(ov0, ov1);
    }
    __syncthreads();
    {
      float ge = geL[tTh];
      float sv0 = ge * Sl[tTh][lvi], sv1 = ge * Sl[tTh][lvi + 1];
      #pragma unroll
      for (int sc = 0; sc < 16; sc++) {
        float g4[4];
        ub4_(*(const uint2*)&SGs[tTh][sc * 4], g4);
        #pragma unroll
        for (int jj = 0; jj < 4; jj++) {
          float2 r2 = *(const float2*)&rl[sc * 4 + jj][lvi];
          sv0 += g4[jj] * r2.x; sv1 += g4[jj] * r2.y;
        }
      }
      Sl[tTh][lvi] = sv0; Sl[tTh][lvi + 1] = sv1;
    }
    __syncthreads();
    if (ch < 31) {
      *(uint4*)&MGs[r0][cc] = p0;
      *(uint4*)&SGs[r0][cc] = p1;
      *(uint4*)&WkBs[r0][cc] = p2;
      *(uint4*)&Wqs[r0][cc] = p3;
      if (tid < 64) geL[tid] = pge;
      bvCur = pbv;
      __syncthreads();
    }
  }
}

// ---------------------------------------------------------------------------
// RMS-norm + INLINE gate (g1 @ Wg2 + bg2, K=64) -> bf16 [M,1024] operand.
// Replaces the standalone gate GEMM dispatch.
// ---------------------------------------------------------------------------
__global__ __launch_bounds__(256) void onorm_pack(
    const ushort* __restrict__ o, const ushort* __restrict__ qkvfgb,
    const ushort* __restrict__ Wg2_1, const float* __restrict__ bg2,
    const float* __restrict__ onw, ushort* __restrict__ out1) {
  int gi = blockIdx.x * 4 + (threadIdx.x >> 6);
  int lane = threadIdx.x & 63;
  int b = gi >> 15, h = (gi >> 11) & 15, t = gi & 2047;
  size_t m = (size_t)(b * T_ + t);
  int c = h * 64 + lane;

  float ov = bf2f(o[(size_t)gi * 64 + lane]);
  float ms = wave_sum64(ov * ov) * (1.f / 64.f);
  float r = rsqrtf(ms + 1e-5f);

  // gate[c] = bg2[c] + sum_j g1[m][j] * Wg2[j][c]   (K=64 inline dot)
  const uint4* g1r = (const uint4*)(qkvfgb + m * QS_ + 3136);
  const uint4* wr = (const uint4*)(Wg2_1 + (size_t)c * 64);
  float gv = bg2[c];
  #pragma unroll
  for (int i2 = 0; i2 < 8; i2++) {
    float a8[8], w8[8];
    ub8_(g1r[i2], a8);
    ub8_(wr[i2], w8);
    #pragma unroll
    for (int j = 0; j < 8; j++) gv += a8[j] * w8[j];
  }

  float val = ov * r * onw[lane] * sigmoidf_(gv);
  out1[m * 1024 + c] = f2bf(val);
}

extern "C" void kernel_launch(void* const* d_in, const int* in_sizes, int n_in,
                              void* d_out, int out_size, void* d_ws, size_t ws_size,
                              hipStream_t stream) {
  const float* hs    = (const float*)d_in[0];
  const float* Wq    = (const float*)d_in[1];
  const float* Wk    = (const float*)d_in[2];
  const float* Wv    = (const float*)d_in[3];
  const float* qcw   = (const float*)d_in[4];
  const float* qcb   = (const float*)d_in[5];
  const float* kcw   = (const float*)d_in[6];
  const float* kcb   = (const float*)d_in[7];
  const float* vcw   = (const float*)d_in[8];
  const float* vcb   = (const float*)d_in[9];
  const float* Wf1   = (const float*)d_in[10];
  const float* Wf2   = (const float*)d_in[11];
  const float* Wb    = (const float*)d_in[12];
  const float* A_log = (const float*)d_in[13];
  const float* dtb   = (const float*)d_in[14];
  const float* Wg1   = (const float*)d_in[15];
  const float* Wg2   = (const float*)d_in[16];
  const float* bg2   = (const float*)d_in[17];
  const float* onw   = (const float*)d_in[18];
  const float* Wo    = (const float*)d_in[19];
  float* out = (float*)d_out;

  char* ws = (char*)d_ws;
  // [0,16M): hs1 (dead after fused GEMM) -> mMGSG [0,32M) -> obuf1 [0,16M) after scan
  // [32,48M): mWkB
  // [48,100M): qkvfgb [M,3328] bf16 (alive thru onorm: g1 cols read inline)
  // [100,116M): grawB (dead after prep) -> oG (written by scan)
  // [116,148.5M): geG (0.5M) + mWqBv (32M)
  // [148.5M..157.2M): Wqkvfgb + Wf2_1 + Wg2_1 + Wo1 (own slot)
  ushort* hs1     = (ushort*)(ws);
  ushort* mMGSG   = (ushort*)(ws);
  ushort* obuf1   = (ushort*)(ws);
  ushort* mWkB    = (ushort*)(ws + 33554432);
  ushort* qkvfgb  = (ushort*)(ws + 50331648);
  ushort* grawB   = (ushort*)(ws + 104857600);
  ushort* oG      = (ushort*)(ws + 104857600);
  float*  geG     = (float*)(ws + 121634816);
  ushort* mWqBv   = (ushort*)(ws + 122159104);
  char*   R4      = ws + 155713536;
  ushort* Wqkvfgb = (ushort*)R4;                        // [3328,1024] 6.8MB
  ushort* Wf2_1   = (ushort*)(R4 + 6815744);            // [1024,64]
  ushort* Wg2_1   = (ushort*)(R4 + 6946816);            // [1024,64]
  ushort* Wo1     = (ushort*)(R4 + 7077888);            // [1024,1024] 2MB own slot

  dim3 blk(256);

  // 1: all input-side packing in one launch (incl. Wo)
  pack_all<<<dim3(PACK_ALL_BLOCKS), blk, 0, stream>>>(
      hs, Wq, Wk, Wv, Wf1, Wg1, Wb, Wf2, Wg2, Wo,
      hs1, Wqkvfgb, Wf2_1, Wg2_1, Wo1);

  // 2: fused q|k|v|f1|g1|b projection (N=3328)
  gemm_glds<ushort><<<dim3(M_ / 128, QS_ / 128), blk, 0, stream>>>(
      hs1, 1024, Wqkvfgb, nullptr, qkvfgb, M_, QS_, 1024);
  // 3: graw = f1 @ Wf2
  gemm_glds<ushort><<<dim3(M_ / 128, 1024 / 128), blk, 0, stream>>>(
      qkvfgb + 3072, QS_, Wf2_1, nullptr, grawB, M_, 1024, 64);

  // 4: chunk-parallel UT-transform precompute
  prep<<<dim3(64, 32), blk, 0, stream>>>(qkvfgb, grawB,
                                         qcw, qcb, kcw, kcb, vcw, vcb,
                                         A_log, dtb, mMGSG, mWkB, mWqBv, geG);

  // 5: sequential chunk scan (oG over dead grawB region)
  scan<<<dim3(64, 4), dim3(512), 0, stream>>>(mMGSG, mWkB, mWqBv, geG, oG);

  // 6: RMS-norm + inline gate (obuf1 over dead mMGSG region)
  onorm_pack<<<dim3((M_ * H_) / 4), blk, 0, stream>>>(
      oG, qkvfgb, Wg2_1, bg2, onw, obuf1);

  // 7: final projection
  gemm_glds<float><<<dim3(M_ / 128, 1024 / 128), blk, 0, stream>>>(
      obuf1, 1024, Wo1, nullptr, out, M_, 1024, 1024);
}

// Round 21
// 508.868 us; speedup vs baseline: 1.2268x; 1.2268x over previous
//
#include <hip/hip_runtime.h>
#include <hip/hip_bf16.h>
#include <math.h>

#define H_ 16
#define HIDDEN_ 1024
#define BATCH_ 4
#define T_ 2048
#define M_ (BATCH_ * T_)   // 8192
#define QS_ 3328           // fused projection row stride: q|k|v|f1|g1|b|pad

typedef __attribute__((ext_vector_type(8))) __bf16 bf16x8;
typedef __attribute__((ext_vector_type(4))) float f32x4;

__device__ __forceinline__ float fexp_(float x) { return __expf(x); }
__device__ __forceinline__ float frcp_(float x) { return __builtin_amdgcn_rcpf(x); }
__device__ __forceinline__ float wave_sum64(float v) {
  #pragma unroll
  for (int m = 32; m >= 1; m >>= 1) v += __shfl_xor(v, m, 64);
  return v;
}
__device__ __forceinline__ float sigmoidf_(float x) { return frcp_(1.f + fexp_(-x)); }
__device__ __forceinline__ float siluf_(float x) { return x * frcp_(1.f + fexp_(-x)); }
__device__ __forceinline__ float bf2f(ushort u) {
  unsigned int x = ((unsigned int)u) << 16;
  return __builtin_bit_cast(float, x);
}
__device__ __forceinline__ ushort f2bf(float f) {   // RNE
  unsigned int x = __builtin_bit_cast(unsigned int, f);
  unsigned int r = (x + 0x7fffu + ((x >> 16) & 1u)) >> 16;
  return (ushort)r;
}
__device__ __forceinline__ void ub2_(uint u, float f[2]) {
  f[0] = bf2f((ushort)u); f[1] = bf2f((ushort)(u >> 16));
}
__device__ __forceinline__ void ub4_(uint2 u, float f[4]) {
  f[0] = bf2f((ushort)u.x); f[1] = bf2f((ushort)(u.x >> 16));
  f[2] = bf2f((ushort)u.y); f[3] = bf2f((ushort)(u.y >> 16));
}
__device__ __forceinline__ void ub8_(uint4 u, float* f) {
  f[0] = bf2f((ushort)u.x); f[1] = bf2f((ushort)(u.x >> 16));
  f[2] = bf2f((ushort)u.y); f[3] = bf2f((ushort)(u.y >> 16));
  f[4] = bf2f((ushort)u.z); f[5] = bf2f((ushort)(u.z >> 16));
  f[6] = bf2f((ushort)u.w); f[7] = bf2f((ushort)(u.w >> 16));
}
__device__ __forceinline__ uint pk2_(float a, float b) {
  return (uint)f2bf(a) | ((uint)f2bf(b) << 16);
}
__device__ __forceinline__ uint2 pk4_(float a, float b, float c, float d) {
  return make_uint2((uint)f2bf(a) | ((uint)f2bf(b) << 16),
                    (uint)f2bf(c) | ((uint)f2bf(d) << 16));
}
__device__ __forceinline__ uint4 pk8_(const float* t) {
  uint4 r;
  r.x = (uint)f2bf(t[0]) | ((uint)f2bf(t[1]) << 16);
  r.y = (uint)f2bf(t[2]) | ((uint)f2bf(t[3]) << 16);
  r.z = (uint)f2bf(t[4]) | ((uint)f2bf(t[5]) << 16);
  r.w = (uint)f2bf(t[6]) | ((uint)f2bf(t[7]) << 16);
  return r;
}
// async global -> LDS, 16B per lane
__device__ __forceinline__ void gl16(const ushort* g, ushort* l) {
  __builtin_amdgcn_global_load_lds(
      (const __attribute__((address_space(1))) unsigned int*)g,
      (__attribute__((address_space(3))) unsigned int*)l, 16, 0, 0);
}

// ---------------------------------------------------------------------------
// pack_all: ONE launch for all input-side packing incl. Wo.
// Region decode by blockIdx; disjoint outputs; pad rows zeroed here.
// ---------------------------------------------------------------------------
__global__ __launch_bounds__(256) void pack_all(
    const float* __restrict__ hs,
    const float* __restrict__ Wq, const float* __restrict__ Wk,
    const float* __restrict__ Wv, const float* __restrict__ Wf1,
    const float* __restrict__ Wg1, const float* __restrict__ Wb,
    const float* __restrict__ Wf2, const float* __restrict__ Wg2,
    const float* __restrict__ Wo,
    ushort* __restrict__ hs1, ushort* __restrict__ Wqkvfgb,
    ushort* __restrict__ Wf2_1, ushort* __restrict__ Wg2_1,
    ushort* __restrict__ Wo1) {
  int blk = blockIdx.x;
  // R0: hs [8192,1024] contiguous copy-cast — 32768 blocks
  if (blk < 32768) {
    size_t tid = (size_t)blk * 256 + threadIdx.x;
    hs1[tid] = f2bf(hs[tid]);
    return;
  }
  blk -= 32768;
  // R1: Wq/Wk/Wv transpose [1024,1024] -> rows [w*1024..) — 3 x 4096 blocks
  if (blk < 12288) {
    int w = blk >> 12;
    size_t tid = (size_t)(blk & 4095) * 256 + threadIdx.x;
    int k = (int)(tid & 1023), n = (int)(tid >> 10);
    const float* W = (w == 0) ? Wq : (w == 1) ? Wk : Wv;
    Wqkvfgb[((size_t)w * 1024 + n) * 1024 + k] = f2bf(W[(size_t)k * 1024 + n]);
    return;
  }
  blk -= 12288;
  // R2: Wf1 [1024,64] -> rows 3072.. — 256 blocks
  if (blk < 256) {
    size_t tid = (size_t)blk * 256 + threadIdx.x;
    int k = (int)(tid & 1023), n = (int)(tid >> 10);
    Wqkvfgb[(size_t)(3072 + n) * 1024 + k] = f2bf(Wf1[(size_t)k * 64 + n]);
    return;
  }
  blk -= 256;
  // R3: Wg1 -> rows 3136.. — 256 blocks
  if (blk < 256) {
    size_t tid = (size_t)blk * 256 + threadIdx.x;
    int k = (int)(tid & 1023), n = (int)(tid >> 10);
    Wqkvfgb[(size_t)(3136 + n) * 1024 + k] = f2bf(Wg1[(size_t)k * 64 + n]);
    return;
  }
  blk -= 256;
  // R4: Wb [1024,16] -> rows 3200.. — 64 blocks
  if (blk < 64) {
    size_t tid = (size_t)blk * 256 + threadIdx.x;
    int k = (int)(tid & 1023), n = (int)(tid >> 10);
    Wqkvfgb[(size_t)(3200 + n) * 1024 + k] = f2bf(Wb[(size_t)k * 16 + n]);
    return;
  }
  blk -= 64;
  // R5: zero pad rows 3216..3327 — 448 blocks
  if (blk < 448) {
    size_t tid = (size_t)blk * 256 + threadIdx.x;
    Wqkvfgb[(size_t)3216 * 1024 + tid] = 0;
    return;
  }
  blk -= 448;
  // R6: Wf2 [64,1024] -> Wf2_1[n][k], rowStride 64 — 256 blocks
  if (blk < 256) {
    size_t tid = (size_t)blk * 256 + threadIdx.x;
    int k = (int)(tid & 63), n = (int)(tid >> 6);
    Wf2_1[(size_t)n * 64 + k] = f2bf(Wf2[(size_t)k * 1024 + n]);
    return;
  }
  blk -= 256;
  // R7: Wg2 -> Wg2_1 — 256 blocks
  if (blk < 256) {
    size_t tid = (size_t)blk * 256 + threadIdx.x;
    int k = (int)(tid & 63), n = (int)(tid >> 6);
    Wg2_1[(size_t)n * 64 + k] = f2bf(Wg2[(size_t)k * 1024 + n]);
    return;
  }
  blk -= 256;
  // R8: Wo transpose [1024,1024] -> Wo1[n][k] — 4096 blocks
  {
    size_t tid = (size_t)blk * 256 + threadIdx.x;
    int k = (int)(tid & 1023), n = (int)(tid >> 10);
    Wo1[(size_t)n * 1024 + k] = f2bf(Wo[(size_t)k * 1024 + n]);
  }
}
#define PACK_ALL_BLOCKS (32768 + 12288 + 256 + 256 + 64 + 448 + 256 + 256 + 4096)

// ---------------------------------------------------------------------------
// bf16 MFMA GEMM, m97 structure + lda + bijective XCD swizzle (nwg%8==0).
// ---------------------------------------------------------------------------
template <typename OutT>
__global__ __launch_bounds__(256) void gemm_glds(
    const ushort* __restrict__ A, int lda, const ushort* __restrict__ Bt,
    const float* __restrict__ bias, OutT* __restrict__ C,
    int M, int N, int K) {
  __shared__ ushort As[128 * 32];
  __shared__ ushort Bs[128 * 32];
  const int tid = threadIdx.x;
  const int gx = gridDim.x;
  const int nwg = gx * gridDim.y;
  const int flat = blockIdx.y * gx + blockIdx.x;
  const int swz = (flat & 7) * (nwg >> 3) + (flat >> 3);
  const int bm = (swz % gx) * 128, bn = (swz / gx) * 128;
  const int wid = tid >> 6, lane = tid & 63;
  const int wm = (wid >> 1) * 64, wn = (wid & 1) * 64;
  const int fr = lane & 15, fq = lane >> 4;
  const int srow = wid * 32 + (lane >> 2);
  const int scol = (lane & 3) * 8;

  f32x4 acc[4][4] = {};

  for (int k0 = 0; k0 < K; k0 += 32) {
    const ushort* gA = A + (size_t)(bm + srow) * lda + k0 + scol;
    const ushort* gB = Bt + (size_t)(bn + srow) * K + k0 + scol;
    gl16(gA, &As[(wid * 32) * 32]);
    gl16(gA + (size_t)16 * lda, &As[(wid * 32 + 16) * 32]);
    gl16(gB, &Bs[(wid * 32) * 32]);
    gl16(gB + (size_t)16 * K, &Bs[(wid * 32 + 16) * 32]);
    __syncthreads();

    bf16x8 af[4], bfr[4];
    #pragma unroll
    for (int i = 0; i < 4; i++) af[i] = *(const bf16x8*)&As[(wm + i * 16 + fr) * 32 + fq * 8];
    #pragma unroll
    for (int j = 0; j < 4; j++) bfr[j] = *(const bf16x8*)&Bs[(wn + j * 16 + fr) * 32 + fq * 8];
    #pragma unroll
    for (int i = 0; i < 4; i++)
      #pragma unroll
      for (int j = 0; j < 4; j++)
        acc[i][j] = __builtin_amdgcn_mfma_f32_16x16x32_bf16(af[i], bfr[j], acc[i][j], 0, 0, 0);
    __syncthreads();
  }

  #pragma unroll
  for (int i = 0; i < 4; i++) {
    #pragma unroll
    for (int j = 0; j < 4; j++) {
      int col = bn + wn + j * 16 + fr;
      float bv = bias ? bias[col] : 0.f;
      #pragma unroll
      for (int r = 0; r < 4; r++) {
        int row = bm + wm + i * 16 + fq * 4 + r;
        float v = acc[i][j][r] + bv;
        if constexpr (sizeof(OutT) == 2) {
          ((ushort*)C)[(size_t)row * N + col] = f2bf(v);
        } else {
          ((float*)C)[(size_t)row * N + col] = v;
        }
      }
    }
  }
}

// unpack element u (0..15) from a 4-row packed conv window x[8] (2 uint4/row)
#define XROW(x, tap, u) \
  bf2f((ushort)(((u) & 1) ? (((const uint*)&(x)[(tap) * 2 + ((u) >> 3)])[((u) >> 1) & 3] >> 16) \
                          : ((const uint*)&(x)[(tap) * 2 + ((u) >> 3)])[((u) >> 1) & 3]))
#define TAPW(w, tap) ((tap) == 0 ? (w).x : (tap) == 1 ? (w).y : (tap) == 2 ? (w).z : (w).w)

// ---------------------------------------------------------------------------
// prep: proven 190us version. DO NOT touch internals.
// ---------------------------------------------------------------------------
__global__ __launch_bounds__(256, 3) void prep(
    const ushort* __restrict__ qkv, const ushort* __restrict__ grawB,
    const float* __restrict__ qcw, const float* __restrict__ qcb,
    const float* __restrict__ kcw, const float* __restrict__ kcb,
    const float* __restrict__ vcw, const float* __restrict__ vcb,
    const float* __restrict__ A_log, const float* __restrict__ dtb,
    ushort* __restrict__ mMGSG, ushort* __restrict__ mWkB,
    ushort* __restrict__ mWqBv, float* __restrict__ geG) {
  const int bh = blockIdx.x, ch = blockIdx.y;
  const int b = bh >> 4, h = bh & 15;
  const int i = bh * 32 + ch;
  const int t0 = ch * 64;
  const int tid = threadIdx.x;
  const int wA = tid >> 6, tA = tid & 63;
  const int tTh = tid >> 2, c4 = tid & 3, kb = c4 * 16;
  const int c0 = h * 64 + kb;

  __shared__ __align__(16) ushort KtU[64][72];
  __shared__ __align__(16) ushort KhU[64][72];
  __shared__ __align__(16) ushort QtU[64][72];
  __shared__ __align__(16) float cM[64][72];
  __shared__ __align__(16) float dlog[17][68];
  __shared__ float betaL[64];
  ushort* cMu = (ushort*)&cM[0][0];
  ushort (*MqkRM)[72] = (ushort(*)[72])cMu;
  ushort (*MkkT)[72] = (ushort(*)[72])(cMu + 64 * 72);
  ushort (*Gt)[72] = KtU;
  ushort (*KhET)[72] = QtU;

  // ---- PH0: conv+SiLU+norm for q,k ----
  {
    const uint4 z4 = make_uint4(0, 0, 0, 0);
    {
      uint4 x[8];
      #pragma unroll
      for (int tap = 0; tap < 4; tap++) {
        int tr = t0 + tTh - 3 + tap;
        if (tr >= 0) {
          const uint4* p = (const uint4*)(qkv + (size_t)(b * T_ + tr) * QS_ + c0);
          x[tap * 2] = p[0]; x[tap * 2 + 1] = p[1];
        } else { x[tap * 2] = z4; x[tap * 2 + 1] = z4; }
      }
      float qa[16], s = 0.f;
      #pragma unroll
      for (int u = 0; u < 16; u++) {
        float4 w = ((const float4*)qcw)[c0 + u];
        float a = qcb[c0 + u];
        #pragma unroll
        for (int tap = 0; tap < 4; tap++) a += XROW(x, tap, u) * TAPW(w, tap);
        a = siluf_(a);
        qa[u] = a; s += a * a;
      }
      s += __shfl_xor(s, 1, 64); s += __shfl_xor(s, 2, 64);
      float qs = 0.125f / (sqrtf(s) + 1e-6f);
      #pragma unroll
      for (int u = 0; u < 16; u++) qa[u] *= qs;
      *(uint4*)&QtU[tTh][kb] = pk8_(&qa[0]);
      *(uint4*)&QtU[tTh][kb + 8] = pk8_(&qa[8]);
    }
    {
      uint4 x[8];
      #pragma unroll
      for (int tap = 0; tap < 4; tap++) {
        int tr = t0 + tTh - 3 + tap;
        if (tr >= 0) {
          const uint4* p = (const uint4*)(qkv + (size_t)(b * T_ + tr) * QS_ + 1024 + c0);
          x[tap * 2] = p[0]; x[tap * 2 + 1] = p[1];
        } else { x[tap * 2] = z4; x[tap * 2 + 1] = z4; }
      }
      float ka[16], s = 0.f;
      #pragma unroll
      for (int u = 0; u < 16; u++) {
        float4 w = ((const float4*)kcw)[c0 + u];
        float a = kcb[c0 + u];
        #pragma unroll
        for (int tap = 0; tap < 4; tap++) a += XROW(x, tap, u) * TAPW(w, tap);
        a = siluf_(a);
        ka[u] = a; s += a * a;
      }
      s += __shfl_xor(s, 1, 64); s += __shfl_xor(s, 2, 64);
      float ks = frcp_(sqrtf(s) + 1e-6f);
      #pragma unroll
      for (int u = 0; u < 16; u++) ka[u] *= ks;
      *(uint4*)&KtU[tTh][kb] = pk8_(&ka[0]);
      *(uint4*)&KtU[tTh][kb + 8] = pk8_(&ka[8]);
    }
    {
      float Aexp = fexp_(A_log[h]);
      const ushort* gr = grawB + (size_t)(b * T_ + t0 + tTh) * 1024 + c0;
      uint4 ga = *(const uint4*)gr;
      uint4 gb = *(const uint4*)(gr + 8);
      float xv[16];
      ub8_(ga, &xv[0]); ub8_(gb, &xv[8]);
      #pragma unroll
      for (int u = 0; u < 16; u++) {
        float x = xv[u] + dtb[c0 + u];
        float sp = (x > 20.f) ? x : __logf(1.f + fexp_(x));
        cM[tTh][kb + u] = -Aexp * sp;
      }
      if (tid < 64)
        betaL[tid] = sigmoidf_(bf2f(qkv[(size_t)(b * T_ + t0 + tid) * QS_ + 3200 + h]));
    }
  }
  __syncthreads();
  // ---- PH2: cumsum within quarters ----
  {
    const int q = wA, k = tA;
    float run = 0.f;
    #pragma unroll
    for (int u = 0; u < 16; u++) { run += cM[q * 16 + u][k]; cM[q * 16 + u][k] = run; }
    dlog[q][k] = run;
  }
  __syncthreads();
  // ---- PH3: segment offsets ----
  {
    const int q = wA, k = tA;
    if (q > 0) {
      float off = dlog[0][k];
      if (q > 1) off += dlog[1][k];
      if (q > 2) off += dlog[2][k];
      #pragma unroll
      for (int u = 0; u < 16; u++) cM[q * 16 + u][k] += off;
    }
  }
  __syncthreads();
  // ---- PH4: block-base log decays ----
  for (int idx = tid; idx < 17 * 64; idx += 256) {
    int P = idx >> 6, k = idx & 63;
    dlog[P][k] = (P == 0) ? 0.f : cM[4 * P - 1][k];
  }
  __syncthreads();
  // ---- PH5: K~/K^/Q~ ----
  {
    const int P5 = tTh >> 2;
    float knv[16], qnv[16];
    ub8_(*(const uint4*)&KtU[tTh][kb], &knv[0]);
    ub8_(*(const uint4*)&KtU[tTh][kb + 8], &knv[8]);
    ub8_(*(const uint4*)&QtU[tTh][kb], &qnv[0]);
    ub8_(*(const uint4*)&QtU[tTh][kb + 8], &qnv[8]);
    float ktv[16], khv[16], qtv[16];
    #pragma unroll
    for (int u = 0; u < 16; u++) {
      int k = kb + u;
      float c = cM[tTh][k], d = dlog[P5][k];
      float e1 = fexp_(c - d);
      float e2 = fexp_(d - c);
      ktv[u] = knv[u] * e1;
      khv[u] = knv[u] * e2;
      qtv[u] = qnv[u] * e1;
    }
    *(uint4*)&KtU[tTh][kb] = pk8_(&ktv[0]);
    *(uint4*)&KtU[tTh][kb + 8] = pk8_(&ktv[8]);
    *(uint4*)&KhU[tTh][kb] = pk8_(&khv[0]);
    *(uint4*)&KhU[tTh][kb + 8] = pk8_(&khv[8]);
    *(uint4*)&QtU[tTh][kb] = pk8_(&qtv[0]);
    *(uint4*)&QtU[tTh][kb + 8] = pk8_(&qtv[8]);
  }
  __syncthreads();
  // ---- PH6: Wq/WkB/bv/ge outputs + Mqk-upper zeroing + M-build ----
  {
    const int P = tTh >> 2;
    float bt = betaL[tTh];
    float qtv[16], ktv[16];
    ub8_(*(const uint4*)&QtU[tTh][kb], &qtv[0]);
    ub8_(*(const uint4*)&QtU[tTh][kb + 8], &qtv[8]);
    ub8_(*(const uint4*)&KtU[tTh][kb], &ktv[0]);
    ub8_(*(const uint4*)&KtU[tTh][kb + 8], &ktv[8]);
    float tq[16], tk[16];
    #pragma unroll
    for (int u = 0; u < 16; u++) {
      int k = kb + u;
      float e = fexp_(dlog[P][k]);
      tq[u] = qtv[u] * e;
      tk[u] = bt * ktv[u] * e;
    }
    ushort* pq = mWqBv + (size_t)i * 8192 + tTh * 64 + kb;
    ushort* pk = mWkB + (size_t)i * 4096 + tTh * 64 + kb;
    *(uint4*)&pq[0] = pk8_(&tq[0]);
    *(uint4*)&pq[8] = pk8_(&tq[8]);
    *(uint4*)&pk[0] = pk8_(&tk[0]);
    *(uint4*)&pk[8] = pk8_(&tk[8]);

    {
      const uint4 z4 = make_uint4(0, 0, 0, 0);
      uint4 x[8];
      #pragma unroll
      for (int tap = 0; tap < 4; tap++) {
        int tr = t0 + tTh - 3 + tap;
        if (tr >= 0) {
          const uint4* p = (const uint4*)(qkv + (size_t)(b * T_ + tr) * QS_ + 2048 + c0);
          x[tap * 2] = p[0]; x[tap * 2 + 1] = p[1];
        } else { x[tap * 2] = z4; x[tap * 2 + 1] = z4; }
      }
      float av[16];
      #pragma unroll
      for (int u = 0; u < 16; u++) {
        float4 w = ((const float4*)vcw)[c0 + u];
        float a = vcb[c0 + u];
        #pragma unroll
        for (int tap = 0; tap < 4; tap++) a += XROW(x, tap, u) * TAPW(w, tap);
        av[u] = bt * siluf_(a);
      }
      ushort* pb = mWqBv + (size_t)i * 8192 + 4096 + tTh * 64 + kb;
      *(uint4*)&pb[0] = pk8_(&av[0]);
      *(uint4*)&pb[8] = pk8_(&av[8]);
    }

    if (tid < 64) geG[(size_t)i * 64 + tid] = fexp_(dlog[16][tid]);

    for (int idx = tid; idx < 64 * 72; idx += 256) {
      int t = idx / 72, s = idx - t * 72;
      if (s >= 64 || (s >> 2) > (t >> 2)) MqkRM[t][s] = 0;
    }

    // M-build: 272 4x4 tiles, R = e^{dP-dJ} <= 1 on the fly
    for (int tile = tid; tile < 272; tile += 256) {
      int mq = (tile >= 136) ? 1 : 0;
      int f = tile - mq * 136;
      int rem = f, P2 = 0;
      while (rem >= P2 + 1) { rem -= P2 + 1; ++P2; }
      int J = rem;
      const ushort (*Xr)[72] = mq ? QtU : KtU;
      float acc[4][4] = {};
      for (int kc = 0; kc < 16; kc++) {
        float av0[4], av1[4], av2[4], av3[4];
        ub4_(*(const uint2*)&Xr[4 * P2 + 0][kc * 4], av0);
        ub4_(*(const uint2*)&Xr[4 * P2 + 1][kc * 4], av1);
        ub4_(*(const uint2*)&Xr[4 * P2 + 2][kc * 4], av2);
        ub4_(*(const uint2*)&Xr[4 * P2 + 3][kc * 4], av3);
        float4 dp = *(const float4*)&dlog[P2][kc * 4];
        float4 dj = *(const float4*)&dlog[J][kc * 4];
        float rv[4] = {fexp_(dp.x - dj.x), fexp_(dp.y - dj.y),
                       fexp_(dp.z - dj.z), fexp_(dp.w - dj.w)};
        #pragma unroll
        for (int c = 0; c < 4; c++) {
          float kv[4];
          ub4_(*(const uint2*)&KhU[4 * J + c][kc * 4], kv);
          float bx = kv[0] * rv[0], by = kv[1] * rv[1], bz = kv[2] * rv[2], bw = kv[3] * rv[3];
          acc[0][c] += av0[0] * bx + av0[1] * by + av0[2] * bz + av0[3] * bw;
          acc[1][c] += av1[0] * bx + av1[1] * by + av1[2] * bz + av1[3] * bw;
          acc[2][c] += av2[0] * bx + av2[1] * by + av2[2] * bz + av2[3] * bw;
          acc[3][c] += av3[0] * bx + av3[1] * by + av3[2] * bz + av3[3] * bw;
        }
      }
      if (mq && P2 == J) {
        #pragma unroll
        for (int c = 0; c < 4; c++)
          #pragma unroll
          for (int r = 0; r < 4; r++)
            if (c > r) acc[r][c] = 0.f;
      }
      if (mq) {
        #pragma unroll
        for (int r = 0; r < 4; r++)
          *(uint2*)&MqkRM[4 * P2 + r][4 * J] =
              pk4_(acc[r][0], acc[r][1], acc[r][2], acc[r][3]);
      } else {
        #pragma unroll
        for (int c = 0; c < 4; c++) {
          uint2 w;
          w.x = (uint)f2bf(acc[0][c]) | ((uint)f2bf(acc[1][c]) << 16);
          w.y = (uint)f2bf(acc[2][c]) | ((uint)f2bf(acc[3][c]) << 16);
          *(uint2*)&MkkT[4 * J + c][4 * P2] = w;
        }
      }
    }
  }
  __syncthreads();
  // ---- PH7: KhET (transposed) into QtU + G-solve writing Gt (transposed) ----
  for (int idx = tid; idx < 4096; idx += 256) {
    int k = idx >> 6, s = idx & 63;
    KhET[k][s] = f2bf(bf2f(KhU[s][k]) * fexp_(dlog[16][k] - dlog[s >> 2][k]));
  }
  {
    const int j = tTh, q = c4;
    float acc[16], gsv[16];
    #pragma unroll
    for (int u = 0; u < 16; u++) { acc[u] = 0.f; gsv[u] = 0.f; }
    for (int s = 0; s < 64; s++) {
      int q0 = s >> 4;
      float g = 0.f;
      if (q == q0) {
        g = ((s == j) ? 1.f : 0.f) - betaL[s] * acc[s & 15];
        gsv[s & 15] = g;
      }
      g = __shfl(g, 4 * (j & 15) + q0, 64);
      #pragma unroll
      for (int u = 0; u < 4; u++) {
        uint2 m2 = *(const uint2*)&MkkT[s][q * 16 + u * 4];
        acc[u * 4 + 0] += bf2f((ushort)m2.x) * g;
        acc[u * 4 + 1] += bf2f((ushort)(m2.x >> 16)) * g;
        acc[u * 4 + 2] += bf2f((ushort)m2.y) * g;
        acc[u * 4 + 3] += bf2f((ushort)(m2.y >> 16)) * g;
      }
    }
    *(uint4*)&Gt[j][q * 16] = pk8_(&gsv[0]);
    *(uint4*)&Gt[j][q * 16 + 8] = pk8_(&gsv[8]);
  }
  __syncthreads();
  // ---- PH8 (MFMA): MG = tril(Mqk)@G, SG = KhET@G ----
  {
    const int wid = tid >> 6, lane = tid & 63;
    const int fr = lane & 15, fq = lane >> 4;
    const int wrow = wid * 16;
    bf16x8 aM[2], aS[2];
    #pragma unroll
    for (int kt = 0; kt < 2; kt++) {
      aM[kt] = *(const bf16x8*)&MqkRM[wrow + fr][kt * 32 + fq * 8];
      aS[kt] = *(const bf16x8*)&KhET[wrow + fr][kt * 32 + fq * 8];
    }
    #pragma unroll
    for (int jt = 0; jt < 4; jt++) {
      bf16x8 bG[2];
      #pragma unroll
      for (int kt = 0; kt < 2; kt++)
        bG[kt] = *(const bf16x8*)&Gt[jt * 16 + fr][kt * 32 + fq * 8];
      f32x4 accM = {}, accS = {};
      #pragma unroll
      for (int kt = 0; kt < 2; kt++) {
        accM = __builtin_amdgcn_mfma_f32_16x16x32_bf16(aM[kt], bG[kt], accM, 0, 0, 0);
        accS = __builtin_amdgcn_mfma_f32_16x16x32_bf16(aS[kt], bG[kt], accS, 0, 0, 0);
      }
      #pragma unroll
      for (int r = 0; r < 4; r++) {
        int row = wrow + fq * 4 + r, col = jt * 16 + fr;
        mMGSG[(size_t)i * 8192 + row * 64 + col] = f2bf(accM[r]);
        mMGSG[(size_t)i * 8192 + 4096 + row * 64 + col] = f2bf(accS[r]);
      }
    }
  }
}

// ---------------------------------------------------------------------------
// scan: 512 threads, 2 v-cols/thread. Grid (64 bh, 4 vq).
// ---------------------------------------------------------------------------
__global__ __launch_bounds__(512) void scan(
    const ushort* __restrict__ mMGSG, const ushort* __restrict__ mWkB,
    const ushort* __restrict__ mWqBv, const float* __restrict__ geG,
    ushort* __restrict__ oG) {
  const int bh = blockIdx.x, vq = blockIdx.y;
  const int tid = threadIdx.x;
  const int tTh = tid >> 3, c8 = tid & 7, lvi = c8 * 2;
  const int r0 = tid >> 3, cc = (tid & 7) * 8;

  __shared__ ushort MGs[64][72], SGs[64][72], WkBs[64][72], Wqs[64][72];
  __shared__ __align__(16) float Sl[64][20], rl[64][20];
  __shared__ float geL[64];

  Sl[tTh][lvi] = 0.f; Sl[tTh][lvi + 1] = 0.f;

  const size_t i0 = (size_t)bh * 32;
  {
    uint4 a0 = *(const uint4*)&mMGSG[i0 * 8192 + tid * 8];
    uint4 b0 = *(const uint4*)&mMGSG[i0 * 8192 + 4096 + tid * 8];
    uint4 c0 = *(const uint4*)&mWkB[i0 * 4096 + (tid & 511) * 8];
    uint4 d0 = *(const uint4*)&mWqBv[i0 * 8192 + tid * 8];
    *(uint4*)&MGs[r0][cc] = a0;
    *(uint4*)&SGs[r0][cc] = b0;
    *(uint4*)&WkBs[r0][cc] = c0;
    *(uint4*)&Wqs[r0][cc] = d0;
    if (tid < 64) geL[tid] = geG[i0 * 64 + tid];
  }
  uint bvCur = *(const uint*)&mWqBv[i0 * 8192 + 4096 + tTh * 64 + vq * 16 + lvi];
  __syncthreads();

  for (int ch = 0; ch < 32; ch++) {
    const size_t i = i0 + ch;
    uint4 p0, p1, p2, p3;
    uint pbv;
    float pge = 0.f;
    if (ch < 31) {
      const size_t i2 = i + 1;
      p0 = *(const uint4*)&mMGSG[i2 * 8192 + tid * 8];
      p1 = *(const uint4*)&mMGSG[i2 * 8192 + 4096 + tid * 8];
      p2 = *(const uint4*)&mWkB[i2 * 4096 + tid * 8];
      p3 = *(const uint4*)&mWqBv[i2 * 8192 + tid * 8];
      pbv = *(const uint*)&mWqBv[i2 * 8192 + 4096 + tTh * 64 + vq * 16 + lvi];
      if (tid < 64) pge = geG[i2 * 64 + tid];
    }
    float rv0, rv1;
    {
      float b2[2]; ub2_(bvCur, b2); rv0 = b2[0]; rv1 = b2[1];
    }
    #pragma unroll
    for (int kc = 0; kc < 16; kc++) {
      float w4[4];
      ub4_(*(const uint2*)&WkBs[tTh][kc * 4], w4);
      #pragma unroll
      for (int jj = 0; jj < 4; jj++) {
        float2 s2 = *(const float2*)&Sl[kc * 4 + jj][lvi];
        rv0 -= w4[jj] * s2.x; rv1 -= w4[jj] * s2.y;
      }
    }
    rl[tTh][lvi] = rv0; rl[tTh][lvi + 1] = rv1;
    __syncthreads();
    {
      float ov0 = 0.f, ov1 = 0.f;
      #pragma unroll
      for (int sc = 0; sc < 16; sc++) {
        float m4[4];
        ub4_(*(const uint2*)&MGs[tTh][sc * 4], m4);
        #pragma unroll
        for (int jj = 0; jj < 4; jj++) {
          float2 r2 = *(const float2*)&rl[sc * 4 + jj][lvi];
          ov0 += m4[jj] * r2.x; ov1 += m4[jj] * r2.y;
        }
      }
      #pragma unroll
      for (int kc = 0; kc < 16; kc++) {
        float q4[4];
        ub4_(*(const uint2*)&Wqs[tTh][kc * 4], q4);
        #pragma unroll
        for (int jj = 0; jj < 4; jj++) {
          float2 s2 = *(const float2*)&Sl[kc * 4 + jj][lvi];
          ov0 += q4[jj] * s2.x; ov1 += q4[jj] * s2.y;
        }
      }
      *(uint*)&oG[i * 4096 + tTh * 64 + vq * 16 + lvi] = pk2_(ov0, ov1);
    }
    __syncthreads();
    {
      float ge = geL[tTh];
      float sv0 = ge * Sl[tTh][lvi], sv1 = ge * Sl[tTh][lvi + 1];
      #pragma unroll
      for (int sc = 0; sc < 16; sc++) {
        float g4[4];
        ub4_(*(const uint2*)&SGs[tTh][sc * 4], g4);
        #pragma unroll
        for (int jj = 0; jj < 4; jj++) {
          float2 r2 = *(const float2*)&rl[sc * 4 + jj][lvi];
          sv0 += g4[jj] * r2.x; sv1 += g4[jj] * r2.y;
        }
      }
      Sl[tTh][lvi] = sv0; Sl[tTh][lvi + 1] = sv1;
    }
    __syncthreads();
    if (ch < 31) {
      *(uint4*)&MGs[r0][cc] = p0;
      *(uint4*)&SGs[r0][cc] = p1;
      *(uint4*)&WkBs[r0][cc] = p2;
      *(uint4*)&Wqs[r0][cc] = p3;
      if (tid < 64) geL[tid] = pge;
      bvCur = pbv;
      __syncthreads();
    }
  }
}

// ---------------------------------------------------------------------------
// RMS-norm + gate (bf16) -> single bf16 [M,1024] GEMM operand.
// ---------------------------------------------------------------------------
__global__ __launch_bounds__(256) void onorm_pack(
    const ushort* __restrict__ o, const ushort* __restrict__ gate,
    const float* __restrict__ onw, ushort* __restrict__ out1) {
  int gi = blockIdx.x * 4 + (threadIdx.x >> 6);
  int lane = threadIdx.x & 63;
  int b = gi >> 15, h = (gi >> 11) & 15, t = gi & 2047;
  float ov = bf2f(o[(size_t)gi * 64 + lane]);
  float ms = wave_sum64(ov * ov) * (1.f / 64.f);
  float r = rsqrtf(ms + 1e-5f);
  float gv = bf2f(gate[(size_t)(b * T_ + t) * 1024 + h * 64 + lane]);
  float val = ov * r * onw[lane] * sigmoidf_(gv);
  out1[(size_t)(b * T_ + t) * 1024 + h * 64 + lane] = f2bf(val);
}

extern "C" void kernel_launch(void* const* d_in, const int* in_sizes, int n_in,
                              void* d_out, int out_size, void* d_ws, size_t ws_size,
                              hipStream_t stream) {
  const float* hs    = (const float*)d_in[0];
  const float* Wq    = (const float*)d_in[1];
  const float* Wk    = (const float*)d_in[2];
  const float* Wv    = (const float*)d_in[3];
  const float* qcw   = (const float*)d_in[4];
  const float* qcb   = (const float*)d_in[5];
  const float* kcw   = (const float*)d_in[6];
  const float* kcb   = (const float*)d_in[7];
  const float* vcw   = (const float*)d_in[8];
  const float* vcb   = (const float*)d_in[9];
  const float* Wf1   = (const float*)d_in[10];
  const float* Wf2   = (const float*)d_in[11];
  const float* Wb    = (const float*)d_in[12];
  const float* A_log = (const float*)d_in[13];
  const float* dtb   = (const float*)d_in[14];
  const float* Wg1   = (const float*)d_in[15];
  const float* Wg2   = (const float*)d_in[16];
  const float* bg2   = (const float*)d_in[17];
  const float* onw   = (const float*)d_in[18];
  const float* Wo    = (const float*)d_in[19];
  float* out = (float*)d_out;

  char* ws = (char*)d_ws;
  // Proven 515us layout (R19):
  // [0,16M): hs1 (dead after fused GEMM) -> mMGSG [0,32M)
  // [32,48M): mWkB
  // [48,100M): qkvfgb (alive thru gate GEMM); oG [48,64M) + obuf1 [64,80M) after
  // [100,116M): grawB -> gate bf16 (gate GEMM after prep)
  // [116,148.5M): geG + mWqBv
  // [148.5M+): Wqkvfgb, Wf2_1, Wg2_1, Wo1 (own slot)
  ushort* hs1     = (ushort*)(ws);
  ushort* mMGSG   = (ushort*)(ws);
  ushort* mWkB    = (ushort*)(ws + 33554432);
  ushort* qkvfgb  = (ushort*)(ws + 50331648);
  ushort* oG      = (ushort*)(ws + 50331648);
  ushort* obuf1   = (ushort*)(ws + 67108864);
  ushort* grawB   = (ushort*)(ws + 104857600);
  ushort* gate    = (ushort*)(ws + 104857600);
  float*  geG     = (float*)(ws + 121634816);
  ushort* mWqBv   = (ushort*)(ws + 122159104);
  char*   R4      = ws + 155713536;
  ushort* Wqkvfgb = (ushort*)R4;                        // [3328,1024] 6.8MB
  ushort* Wf2_1   = (ushort*)(R4 + 6815744);            // [1024,64]
  ushort* Wg2_1   = (ushort*)(R4 + 6946816);            // [1024,64]
  ushort* Wo1     = (ushort*)(R4 + 7077888);            // [1024,1024] 2MB own slot

  dim3 blk(256);

  // 1: all input-side packing in one launch (incl. Wo)
  pack_all<<<dim3(PACK_ALL_BLOCKS), blk, 0, stream>>>(
      hs, Wq, Wk, Wv, Wf1, Wg1, Wb, Wf2, Wg2, Wo,
      hs1, Wqkvfgb, Wf2_1, Wg2_1, Wo1);

  // 2: fused q|k|v|f1|g1|b projection (N=3328)
  gemm_glds<ushort><<<dim3(M_ / 128, QS_ / 128), blk, 0, stream>>>(
      hs1, 1024, Wqkvfgb, nullptr, qkvfgb, M_, QS_, 1024);
  // 3: graw = f1 @ Wf2
  gemm_glds<ushort><<<dim3(M_ / 128, 1024 / 128), blk, 0, stream>>>(
      qkvfgb + 3072, QS_, Wf2_1, nullptr, grawB, M_, 1024, 64);

  // 4: chunk-parallel UT-transform precompute
  prep<<<dim3(64, 32), blk, 0, stream>>>(qkvfgb, grawB,
                                         qcw, qcb, kcw, kcb, vcw, vcb,
                                         A_log, dtb, mMGSG, mWkB, mWqBv, geG);

  // 5: gate = g1 @ Wg2 + bg2 (MFMA; writes over dead grawB region)
  gemm_glds<ushort><<<dim3(M_ / 128, 1024 / 128), blk, 0, stream>>>(
      qkvfgb + 3136, QS_, Wg2_1, bg2, gate, M_, 1024, 64);

  // 6: sequential chunk scan (oG over dead qkvfgb head)
  scan<<<dim3(64, 4), dim3(512), 0, stream>>>(mMGSG, mWkB, mWqBv, geG, oG);

  // 7: RMS-norm + gate
  onorm_pack<<<dim3((M_ * H_) / 4), blk, 0, stream>>>(oG, gate, onw, obuf1);

  // 8: final projection
  gemm_glds<float><<<dim3(M_ / 128, 1024 / 128), blk, 0, stream>>>(
      obuf1, 1024, Wo1, nullptr, out, M_, 1024, 1024);
}